// Round 8
// baseline (221.260 us; speedup 1.0000x reference)
//
#include <hip/hip_runtime.h>

// Sizes (fixed by the reference)
#define NB_B 16
#define NN   1024
#define NW   32
#define NCS  12
#define NH1  40
#define NH2  10

// Workspace layout (float offsets). Scratch region is time-shared:
//   Pf (3*16*40*1024) -> P1b (2*1024*640) -> P2 (8*1024*160) -> P3 (16*1024*16)
#define OFF_DIS  0
#define OFF_G0T  1024
#define OFF_X1   (OFF_G0T + NN*NB_B*NH1)
#define OFF_G1   (OFF_X1 + NN*NB_B*NH1)
#define OFF_G2   (OFF_G1 + NN*NB_B*NH2)
#define OFF_SCR  (OFF_G2 + NN*NB_B)

// ---------------------------------------------------------------------------
// dis[i] = rsqrt(max(1, 1 + sum_j A0[i,j]))   (A batch-tiled: use batch 0)
__global__ __launch_bounds__(256) void k_dis(const float* __restrict__ A0,
                                             float* __restrict__ dis) {
    int i = blockIdx.x;
    const float* row = A0 + (size_t)i * NN;
    float s = 0.f;
    for (int j = threadIdx.x; j < NN; j += 256) s += row[j];
#pragma unroll
    for (int off = 32; off > 0; off >>= 1) s += __shfl_down(s, off);
    __shared__ float red[4];
    int lane = threadIdx.x & 63, wv = threadIdx.x >> 6;
    if (lane == 0) red[wv] = s;
    __syncthreads();
    if (threadIdx.x == 0) {
        float deg = 1.f + red[0] + red[1] + red[2] + red[3];
        dis[i] = rsqrtf(fmaxf(deg, 1.f));
    }
}

// ---------------------------------------------------------------------------
// Fused conv-branch + relu + (xconv @ Wg1) partial.
// Block = 256 nodes, ONE hq (all 4 waves share the LDS Wg1 slice).
// Grid: (4 ntiles * 4 hq, 16 b, 3 br). Conv in regs; Wg1 hq-slice staged
// packed in LDS ([row][10]) -> broadcast ds_read in the inner loop.
// Writes Pf[br][b][h][n]  (pre-dis, pre-bias), coalesced along n.
template <int KSZ, int LK, int DBASE, int BR>
__device__ __forceinline__ void feat_body(const float* __restrict__ x,
                                          const float* __restrict__ Wc,
                                          const float* __restrict__ bc,
                                          const float* __restrict__ Wg1,
                                          float* __restrict__ Pf,
                                          float* __restrict__ wlds) {
    const int ROWS = NCS * LK;
    int tid = threadIdx.x;
    int nt = blockIdx.x >> 2;
    int hq = blockIdx.x & 3;
    int n = nt * 256 + tid;
    int b = blockIdx.y;

    // Stage packed Wg1 slice: wlds[d*10+u] = Wg1[(DBASE+d)*40 + hq*10 + u]
    for (int idx = tid; idx < ROWS * 10; idx += 256) {
        int d = idx / 10, u = idx - d * 10;
        wlds[idx] = Wg1[(size_t)(DBASE + d) * NH1 + hq * 10 + u];
    }
    __syncthreads();

    float xs[NW];
#pragma unroll
    for (int w = 0; w < NW; ++w) xs[w] = x[((size_t)b * NW + w) * NN + n];

    float acc[10];
#pragma unroll
    for (int u = 0; u < 10; ++u) acc[u] = 0.f;

    for (int cs = 0; cs < NCS; ++cs) {
        float wk[KSZ];
#pragma unroll
        for (int t = 0; t < KSZ; ++t) wk[t] = Wc[cs * KSZ + t];
        float bb = bc[cs];
        const float* wbase = wlds + cs * (LK * 10);
#pragma unroll
        for (int l = 0; l < LK; ++l) {
            float s = bb;
#pragma unroll
            for (int t = 0; t < KSZ; ++t) s = fmaf(xs[l + t], wk[t], s);
            s = fmaxf(s, 0.f);
            const float* wr = wbase + l * 10;  // uniform addr -> broadcast
#pragma unroll
            for (int u = 0; u < 10; ++u) acc[u] = fmaf(s, wr[u], acc[u]);
        }
    }
    float* dst = Pf + (((size_t)BR * NB_B + b) * NH1 + hq * 10) * NN + n;
#pragma unroll
    for (int u = 0; u < 10; ++u) dst[(size_t)u * NN] = acc[u];
}

__global__ __launch_bounds__(256) void k_feat(
    const float* __restrict__ x, const float* __restrict__ W1,
    const float* __restrict__ b1, const float* __restrict__ W2,
    const float* __restrict__ b2, const float* __restrict__ W3,
    const float* __restrict__ b3, const float* __restrict__ Wg1,
    float* __restrict__ Pf) {
    __shared__ float wlds[3600];
    int br = blockIdx.z;
    if (br == 0)      feat_body<3, 30, 0,   0>(x, W1, b1, Wg1, Pf, wlds);
    else if (br == 1) feat_body<5, 28, 360, 1>(x, W2, b2, Wg1, Pf, wlds);
    else              feat_body<7, 26, 696, 2>(x, W3, b3, Wg1, Pf, wlds);
}

// ---------------------------------------------------------------------------
// G0T[c][n] = dis[n] * sum_br Pf[br][b][h][n]   (c = b*40+h)
__global__ __launch_bounds__(256) void k_combine(const float* __restrict__ Pf,
                                                 const float* __restrict__ dis,
                                                 float* __restrict__ G0T) {
    int c = blockIdx.x;  // < 640
    const float* p = Pf + (size_t)c * NN;
    float* dst = G0T + (size_t)c * NN;
#pragma unroll
    for (int k = 0; k < 4; ++k) {
        int n = k * 256 + threadIdx.x;
        float v = p[n] + p[(size_t)NB_B * NH1 * NN + n] +
                  p[(size_t)2 * NB_B * NH1 * NN + n];
        dst[n] = dis[n] * v;
    }
}

// ---------------------------------------------------------------------------
// K-split GEMM with +I folded into A staging:
// P1[z][i][c] = sum_{j in Kz} (A0+I)[i,j]*G0T[c][j]
// z=0 -> P1a (X1 buffer); z=1,2 -> P1b.
__global__ __launch_bounds__(256) void k_prop1s(const float* __restrict__ A0,
                                                const float* __restrict__ G0T,
                                                float* __restrict__ P1a,
                                                float* __restrict__ P1b) {
    __shared__ float As[32][68];  // As[k][i] (transposed)
    __shared__ float Bs[32][68];  // Bs[k][c]
    int tid = threadIdx.x;
    int n0 = blockIdx.x * 64;
    int i0 = blockIdx.y * 64;
    int z  = blockIdx.z;
    int kc0 = z * 352;
    int kc1 = (z == 2) ? NN : kc0 + 352;
    float* P = (z == 0) ? P1a : (P1b + (size_t)(z - 1) * NN * 640);
    int tx = tid & 15, ty = tid >> 4;
    float acc[4][4] = {};
    for (int kc = kc0; kc < kc1; kc += 32) {
#pragma unroll
        for (int v = 0; v < 2; ++v) {
            int fid = tid + v * 256;
            int r = fid >> 3, c4 = (fid & 7) * 4;
            float4 a = *(const float4*)&A0[(size_t)(i0 + r) * NN + kc + c4];
            int dd = (i0 + r) - (kc + c4);  // +I diagonal fold
            a.x += (dd == 0) ? 1.f : 0.f;
            a.y += (dd == 1) ? 1.f : 0.f;
            a.z += (dd == 2) ? 1.f : 0.f;
            a.w += (dd == 3) ? 1.f : 0.f;
            As[c4 + 0][r] = a.x; As[c4 + 1][r] = a.y;
            As[c4 + 2][r] = a.z; As[c4 + 3][r] = a.w;
            float4 g = *(const float4*)&G0T[(size_t)(n0 + r) * NN + kc + c4];
            Bs[c4 + 0][r] = g.x; Bs[c4 + 1][r] = g.y;
            Bs[c4 + 2][r] = g.z; Bs[c4 + 3][r] = g.w;
        }
        __syncthreads();
#pragma unroll
        for (int kk = 0; kk < 32; ++kk) {
            float4 av = *(const float4*)&As[kk][ty * 4];
            float4 bv = *(const float4*)&Bs[kk][tx * 4];
            acc[0][0] = fmaf(av.x, bv.x, acc[0][0]);
            acc[0][1] = fmaf(av.x, bv.y, acc[0][1]);
            acc[0][2] = fmaf(av.x, bv.z, acc[0][2]);
            acc[0][3] = fmaf(av.x, bv.w, acc[0][3]);
            acc[1][0] = fmaf(av.y, bv.x, acc[1][0]);
            acc[1][1] = fmaf(av.y, bv.y, acc[1][1]);
            acc[1][2] = fmaf(av.y, bv.z, acc[1][2]);
            acc[1][3] = fmaf(av.y, bv.w, acc[1][3]);
            acc[2][0] = fmaf(av.z, bv.x, acc[2][0]);
            acc[2][1] = fmaf(av.z, bv.y, acc[2][1]);
            acc[2][2] = fmaf(av.z, bv.z, acc[2][2]);
            acc[2][3] = fmaf(av.z, bv.w, acc[2][3]);
            acc[3][0] = fmaf(av.w, bv.x, acc[3][0]);
            acc[3][1] = fmaf(av.w, bv.y, acc[3][1]);
            acc[3][2] = fmaf(av.w, bv.z, acc[3][2]);
            acc[3][3] = fmaf(av.w, bv.w, acc[3][3]);
        }
        __syncthreads();
    }
    int col = n0 + tx * 4;
#pragma unroll
    for (int iy = 0; iy < 4; ++iy) {
        int i = i0 + ty * 4 + iy;
        float4 o;
        o.x = acc[iy][0]; o.y = acc[iy][1]; o.z = acc[iy][2]; o.w = acc[iy][3];
        *(float4*)&P[(size_t)i * 640 + col] = o;
    }
}

// ---------------------------------------------------------------------------
// Finish layer 1 in place: X1[i][c] = relu(dis[i]*(P1a+P1b0+P1b1)+bg1[h])
// (diag already folded into propagate). P1a aliases X1. Pure streaming.
__global__ __launch_bounds__(256) void k_fin1(float* __restrict__ P1a,
                                              const float* __restrict__ P1b,
                                              const float* __restrict__ dis,
                                              const float* __restrict__ bg1) {
    int f4 = blockIdx.x * 256 + threadIdx.x;  // < 163840
    int i = f4 / 160;
    int c4 = (f4 % 160) * 4;
    float4 a = ((const float4*)P1a)[f4];
    float4 b = ((const float4*)P1b)[f4];
    float4 c = ((const float4*)P1b)[f4 + NN * 160];
    int h0 = c4 % 40;
    float4 bv = *(const float4*)&bg1[h0];
    float di = dis[i];
    float4 o;
    o.x = fmaxf(di * (a.x + b.x + c.x) + bv.x, 0.f);
    o.y = fmaxf(di * (a.y + b.y + c.y) + bv.y, 0.f);
    o.z = fmaxf(di * (a.z + b.z + c.z) + bv.z, 0.f);
    o.w = fmaxf(di * (a.w + b.w + c.w) + bv.w, 0.f);
    ((float4*)P1a)[f4] = o;  // X1 in place
}

// ---------------------------------------------------------------------------
// G1[i][b][m] = dis[i] * sum_h X1[i][b][h] * Wg2[h][m]
__global__ __launch_bounds__(256) void k_x1w2(const float* __restrict__ X1,
                                              const float* __restrict__ Wg2,
                                              const float* __restrict__ dis,
                                              float* __restrict__ G1) {
    __shared__ float w2[NH1 * NH2];
    int tid = threadIdx.x;
    for (int idx = tid; idx < NH1 * NH2; idx += 256) w2[idx] = Wg2[idx];
    __syncthreads();
    int t = blockIdx.x * 256 + tid;  // < 16384
    int i = t >> 4, b = t & 15;
    const float* xr = X1 + (size_t)i * 640 + b * 40;
    float di = dis[i];
    float o[10];
#pragma unroll
    for (int m = 0; m < 10; ++m) o[m] = 0.f;
#pragma unroll
    for (int h4 = 0; h4 < 10; ++h4) {
        float4 xv = *(const float4*)&xr[h4 * 4];
#pragma unroll
        for (int m = 0; m < 10; ++m) {
            o[m] = fmaf(xv.x, w2[(h4 * 4 + 0) * 10 + m], o[m]);
            o[m] = fmaf(xv.y, w2[(h4 * 4 + 1) * 10 + m], o[m]);
            o[m] = fmaf(xv.z, w2[(h4 * 4 + 2) * 10 + m], o[m]);
            o[m] = fmaf(xv.w, w2[(h4 * 4 + 3) * 10 + m], o[m]);
        }
    }
    float* dst = G1 + (size_t)i * 160 + b * 10;
#pragma unroll
    for (int m = 0; m < 10; ++m) dst[m] = di * o[m];
}

// ---------------------------------------------------------------------------
// P2[kc][i][c] = sum_{j in chunk kc} (A0+I)[i,j] * G1[j][c]   (c=b*10+m, 160)
// K-split x8, 32-row tiles -> 256 blocks; micro 2x10.
__global__ __launch_bounds__(256) void k_prop2(const float* __restrict__ A0,
                                               const float* __restrict__ G1,
                                               float* __restrict__ P2) {
    __shared__ float As[32][36];
    __shared__ float Gs[32][164];
    int tid = threadIdx.x;
    int kb = blockIdx.x * 128;
    int i0 = blockIdx.y * 32;
    int cg = tid & 15, ig = tid >> 4;
    float acc[2][10] = {};
    for (int kc = 0; kc < 128; kc += 32) {
        {
            int r = tid >> 3, c4 = (tid & 7) * 4;
            float4 a = *(const float4*)&A0[(size_t)(i0 + r) * NN + kb + kc + c4];
            int dd = (i0 + r) - (kb + kc + c4);
            a.x += (dd == 0) ? 1.f : 0.f;
            a.y += (dd == 1) ? 1.f : 0.f;
            a.z += (dd == 2) ? 1.f : 0.f;
            a.w += (dd == 3) ? 1.f : 0.f;
            As[c4 + 0][r] = a.x; As[c4 + 1][r] = a.y;
            As[c4 + 2][r] = a.z; As[c4 + 3][r] = a.w;
        }
#pragma unroll
        for (int v = 0; v < 5; ++v) {
            int fid = tid + v * 256;  // < 1280
            int r = fid / 40, c4 = (fid % 40) * 4;
            *(float4*)&Gs[r][c4] =
                *(const float4*)&G1[(size_t)(kb + kc + r) * 160 + c4];
        }
        __syncthreads();
#pragma unroll
        for (int kk = 0; kk < 32; ++kk) {
            float a0 = As[kk][ig * 2 + 0];
            float a1 = As[kk][ig * 2 + 1];
#pragma unroll
            for (int u = 0; u < 10; ++u) {
                float g = Gs[kk][cg + 16 * u];
                acc[0][u] = fmaf(a0, g, acc[0][u]);
                acc[1][u] = fmaf(a1, g, acc[1][u]);
            }
        }
        __syncthreads();
    }
#pragma unroll
    for (int iy = 0; iy < 2; ++iy) {
        float* dst = P2 + ((size_t)blockIdx.x * NN + i0 + ig * 2 + iy) * 160;
#pragma unroll
        for (int u = 0; u < 10; ++u) dst[cg + 16 * u] = acc[iy][u];
    }
}

// ---------------------------------------------------------------------------
// Reduce P2, finish layer 2, fuse X2 @ Wg3:  G2[i][b] = dis[i]*sum_m X2*Wg3
__global__ __launch_bounds__(256) void k_red2(const float* __restrict__ P2,
                                              const float* __restrict__ dis,
                                              const float* __restrict__ bg2,
                                              const float* __restrict__ Wg3,
                                              float* __restrict__ G2) {
    int t = blockIdx.x * 256 + threadIdx.x;  // < 16384
    int i = t >> 4, b = t & 15;
    float s[10];
#pragma unroll
    for (int m = 0; m < 10; ++m) s[m] = 0.f;
    for (int kc = 0; kc < 8; ++kc) {
        const float* p = P2 + (size_t)kc * NN * 160 + (size_t)i * 160 + b * 10;
#pragma unroll
        for (int m = 0; m < 10; ++m) s[m] += p[m];
    }
    float di = dis[i];
    float g2 = 0.f;
#pragma unroll
    for (int m = 0; m < 10; ++m) {
        float x2 = fmaxf(di * s[m] + bg2[m], 0.f);
        g2 = fmaf(x2, Wg3[m], g2);
    }
    G2[(size_t)i * 16 + b] = di * g2;
}

// ---------------------------------------------------------------------------
// P3[kc][i][b] = sum_{j in chunk} (A0+I)[i,j]*G2[j][b]
// K-split x16 (64 j), 32-row tiles -> 512 blocks.
__global__ __launch_bounds__(256) void k_prop3(const float* __restrict__ A0,
                                               const float* __restrict__ G2,
                                               float* __restrict__ P3) {
    __shared__ float As[64][36];   // As[j][i]
    __shared__ float G2s[64][16];
    int tid = threadIdx.x;
    int kb = blockIdx.x * 64;
    int i0 = blockIdx.y * 32;
    {
        int r = tid >> 2, c4 = (tid & 3) * 4;
        *(float4*)&G2s[r][c4] = *(const float4*)&G2[(size_t)(kb + r) * 16 + c4];
    }
#pragma unroll
    for (int v = 0; v < 2; ++v) {
        int fid = tid + v * 256;  // < 512
        int r = fid >> 4, c4 = (fid & 15) * 4;
        float4 a = *(const float4*)&A0[(size_t)(i0 + r) * NN + kb + c4];
        int dd = (i0 + r) - (kb + c4);
        a.x += (dd == 0) ? 1.f : 0.f;
        a.y += (dd == 1) ? 1.f : 0.f;
        a.z += (dd == 2) ? 1.f : 0.f;
        a.w += (dd == 3) ? 1.f : 0.f;
        As[c4 + 0][r] = a.x; As[c4 + 1][r] = a.y;
        As[c4 + 2][r] = a.z; As[c4 + 3][r] = a.w;
    }
    __syncthreads();
    int il = tid >> 3, c0 = (tid & 7) * 2;
    float acc0 = 0.f, acc1 = 0.f;
#pragma unroll
    for (int kk = 0; kk < 64; ++kk) {
        float a = As[kk][il];
        acc0 = fmaf(a, G2s[kk][c0 + 0], acc0);
        acc1 = fmaf(a, G2s[kk][c0 + 1], acc1);
    }
    size_t base = (size_t)blockIdx.x * NN * 16 + (size_t)(i0 + il) * 16 + c0;
    P3[base + 0] = acc0;
    P3[base + 1] = acc1;
}

// ---------------------------------------------------------------------------
// out[b][i] = dis[i]*sum_kc P3 + bg3   (diag folded into prop3)
__global__ __launch_bounds__(256) void k_red3(const float* __restrict__ P3,
                                              const float* __restrict__ dis,
                                              const float* __restrict__ bg3,
                                              float* __restrict__ out) {
    int t = blockIdx.x * 256 + threadIdx.x;  // < 16384
    int i = t >> 4, b = t & 15;
    float s = 0.f;
#pragma unroll
    for (int kc = 0; kc < 16; ++kc) s += P3[(size_t)kc * NN * 16 + i * 16 + b];
    out[(size_t)b * NN + i] = dis[i] * s + bg3[0];
}

// ---------------------------------------------------------------------------
extern "C" void kernel_launch(void* const* d_in, const int* in_sizes, int n_in,
                              void* d_out, int out_size, void* d_ws,
                              size_t ws_size, hipStream_t stream) {
    (void)in_sizes; (void)n_in; (void)out_size; (void)ws_size;
    const float* x   = (const float*)d_in[0];
    const float* A   = (const float*)d_in[1];  // batch-tiled; use batch 0 only
    const float* W1  = (const float*)d_in[2];
    const float* b1  = (const float*)d_in[3];
    const float* W2  = (const float*)d_in[4];
    const float* b2  = (const float*)d_in[5];
    const float* W3  = (const float*)d_in[6];
    const float* b3  = (const float*)d_in[7];
    const float* Wg1 = (const float*)d_in[8];
    const float* bg1 = (const float*)d_in[9];
    const float* Wg2 = (const float*)d_in[10];
    const float* bg2 = (const float*)d_in[11];
    const float* Wg3 = (const float*)d_in[12];
    const float* bg3 = (const float*)d_in[13];
    float* ws  = (float*)d_ws;
    float* dis = ws + OFF_DIS;
    float* G0T = ws + OFF_G0T;
    float* X1  = ws + OFF_X1;   // also P1a (K-split partial z=0)
    float* G1  = ws + OFF_G1;
    float* G2  = ws + OFF_G2;
    float* SCR = ws + OFF_SCR;  // Pf -> P1b -> P2 -> P3 (time-shared)
    float* out = (float*)d_out;

    k_dis<<<NN, 256, 0, stream>>>(A, dis);
    k_feat<<<dim3(16, 16, 3), 256, 0, stream>>>(x, W1, b1, W2, b2, W3, b3, Wg1, SCR);
    k_combine<<<640, 256, 0, stream>>>(SCR, dis, G0T);
    k_prop1s<<<dim3(10, 16, 3), 256, 0, stream>>>(A, G0T, X1, SCR);
    k_fin1<<<640, 256, 0, stream>>>(X1, SCR, dis, bg1);
    k_x1w2<<<64, 256, 0, stream>>>(X1, Wg2, dis, G1);
    k_prop2<<<dim3(8, 32), 256, 0, stream>>>(A, G1, SCR);
    k_red2<<<64, 256, 0, stream>>>(SCR, dis, bg2, Wg3, G2);
    k_prop3<<<dim3(16, 32), 256, 0, stream>>>(A, G2, SCR);
    k_red3<<<64, 256, 0, stream>>>(SCR, dis, bg3, out);
}